// Round 5
// baseline (522.454 us; speedup 1.0000x reference)
//
#include <hip/hip_runtime.h>
#include <math.h>

#define NB 16
#define DD 256       // D (in channels)
#define LL 16384     // H*W
#define DO 256       // D_OUT

// workspace float offsets
#define WS_QKP   0                    // 8*256 qk partials
#define WS_QW2P  2048                 // 8*256 qw2 partials
#define WS_W1T   4096                 // 65536  w1t[f][o]
#define WS_VWT   (WS_W1T + 65536)     // 65536  v_wt[d][o]
#define WS_M     (WS_VWT + 65536)     // 16*512
#define WS_DEN   (WS_M + NB*512)      // 16*512
#define WS_NUM   (WS_DEN + NB*512)    // 16*512*256 = 2097152
#define WS_CNT   (WS_NUM + NB*512*256) // 1 uint ticket
// total ~2.25M floats (~9 MB) of d_ws

__device__ __forceinline__ float gelu_tanh(float u) {
    float u3 = u*u*u;
    return 0.5f*u*(1.0f + tanhf(0.7978845608028654f*(u + 0.044715f*u3)));
}

// LDS-only barrier: NO vmcnt drain (keeps global prefetch loads in flight).
// Producer-safe: own ds_writes retired (lgkmcnt 0) before s_barrier.
#define LGKMBAR() do {                                          \
    asm volatile("s_waitcnt lgkmcnt(0)" ::: "memory");          \
    __builtin_amdgcn_s_barrier();                               \
    asm volatile("" ::: "memory");                              \
} while (0)

// ---- K0: grid 528.
// blocks 0..7   : qk partial over o-chunk   (k_w^T q)
// blocks 8..15  : qw2 partial over o-chunk  (w2^T q)
// blocks 16..271: w1t[f][o] = w1[o][f]
// blocks 272..527: v_wt[d][o] = v_w[o][d]
// block 0 also zeroes the ticket counter (ws arrives poisoned).
// c1=k_b.q, c2=b2.q are constant over l,n -> softmax-invariant -> dropped.
__global__ __launch_bounds__(256) void k0(const float* __restrict__ query,
        const float* __restrict__ k_w, const float* __restrict__ w2,
        const float* __restrict__ w1, const float* __restrict__ v_w,
        float* __restrict__ ws) {
    int t = threadIdx.x, b = blockIdx.x;
    if (b == 0 && t == 0) *(unsigned*)(ws + WS_CNT) = 0u;
    if (b < 16) {
        bool is_k = (b < 8);
        int c = b & 7;
        const float* M = is_k ? k_w : w2;
        float a = 0.f;
        #pragma unroll
        for (int oi = 0; oi < 32; ++oi) {
            int o = c*32 + oi;
            a += M[o*DD + t] * query[o];    // row coalesced, query[o] scalar
        }
        ws[(is_k ? WS_QKP : WS_QW2P) + c*256 + t] = a;
    } else if (b < 272) {
        int f = b - 16;
        ws[WS_W1T + f*DO + t] = w1[t*DO + f];
    } else {
        int d = b - 272;
        ws[WS_VWT + d*DO + t] = v_w[t*DD + d];
    }
}

// ---- K2 fused: grid 512 (lb), 256 threads. Block owns l = lb*32 .. +32,
// loops over all 16 n. Prologue computes pq for its 32 l (MLP, w1t from L2).
// Single-shot softmax per (n,lb): m, den, num partials -> ws. All barriers
// are lgkm-only so x prefetch loads survive them (continuous HBM stream).
// Ticketed tail: last 16 blocks to finish each combine one n (k3's job),
// overlapped with straggler blocks. Deadlock-free: every dispatched block
// increments BEFORE spinning; spinners (<=16 blocks) can never occupy all
// slots, so remaining blocks always dispatch, finish, and release the spin.
__global__ __launch_bounds__(256, 2) void k2_fused(const float* __restrict__ x,
        const float* __restrict__ Wr, const float* __restrict__ b1,
        const float* __restrict__ v_b, float* __restrict__ out,
        float* __restrict__ ws) {
    __shared__ __align__(16) float featsT[256*36];   // 36 KB: [f][32 l pad 36]
    __shared__ float qk_s[DD];
    __shared__ float pq_s[32];
    __shared__ __align__(16) float part[128];
    __shared__ __align__(16) float e_s[32];
    __shared__ unsigned ticket_s;
    int t = threadIdx.x;
    int lb = blockIdx.x;
    int l0 = lb * 32;
    int w = t >> 6, lane = t & 63;
    int dld = t >> 3, li4 = (t & 7) * 4;   // thread owns d=i2*32+dld, l=l0+li4..+3
    const float* xb = x + l0 + li4;

    // qk partials first (small, L2-resident; vmcnt retires in order so these
    // land before the big x prefetch and unblock the first barrier early)
    float qp[8];
    #pragma unroll
    for (int c = 0; c < 8; ++c) qp[c] = ws[WS_QKP + c*256 + t];

    // issue x prefetch for n=0,1 (flows under the prologue)
    float4 vb[2][8];
    #pragma unroll
    for (int i2 = 0; i2 < 8; ++i2)
        vb[0][i2] = *(const float4*)(xb + ((size_t)(0*DD + i2*32 + dld))*LL);
    #pragma unroll
    for (int i2 = 0; i2 < 8; ++i2)
        vb[1][i2] = *(const float4*)(xb + ((size_t)(1*DD + i2*32 + dld))*LL);

    float aqk = qp[0]+qp[1]+qp[2]+qp[3]+qp[4]+qp[5]+qp[6]+qp[7];
    qk_s[t] = aqk;

    // featsT[f][lr]: f = t, lr = 0..31 (cos for t<128, sin else)
    {
        int r = t & 127;
        float wr0 = Wr[r*2], wr1 = Wr[r*2+1];
        bool is_cos = (t < 128);
        #pragma unroll 8
        for (int lr = 0; lr < 32; ++lr) {
            int l = l0 + lr;
            int i = l >> 7, j = l & 127;
            float y = -1.0f + (2.0f/127.0f)*(float)i;
            float xg = -1.0f + (2.0f/127.0f)*(float)j;
            float p = y*wr0 + xg*wr1;
            featsT[t*36 + lr] = (is_cos ? cosf(p) : sinf(p)) * 0.0625f;
        }
    }
    LGKMBAR();                         // featsT + qk_s visible

    // ---- MLP prologue: wave w owns l = l0 + w*8 .. +8; lane owns o4 = lane*4.
    // wv streamed from ws[W1T] (L2-resident, identical across waves -> L1 hits).
    float z[8][4];
    #pragma unroll
    for (int a = 0; a < 8; ++a) { z[a][0]=0.f; z[a][1]=0.f; z[a][2]=0.f; z[a][3]=0.f; }
    int o4 = lane * 4;
    const float* w1p = ws + WS_W1T + o4;
    const float* frp = featsT + w*8;
    #pragma unroll 4
    for (int f = 0; f < 256; ++f) {
        float4 wv = *(const float4*)(w1p + f*256);       // global b128, L1/L2
        float4 fa = *(const float4*)(frp + f*36);        // LDS broadcast b128
        float4 fbq = *(const float4*)(frp + f*36 + 4);   // LDS broadcast b128
        float fv[8] = {fa.x,fa.y,fa.z,fa.w,fbq.x,fbq.y,fbq.z,fbq.w};
        #pragma unroll
        for (int lr = 0; lr < 8; ++lr) {
            z[lr][0] += fv[lr]*wv.x; z[lr][1] += fv[lr]*wv.y;
            z[lr][2] += fv[lr]*wv.z; z[lr][3] += fv[lr]*wv.w;
        }
    }
    {
        float4 qwv; qwv.x=0.f; qwv.y=0.f; qwv.z=0.f; qwv.w=0.f;
        #pragma unroll
        for (int c = 0; c < 8; ++c) {
            float4 p = *(const float4*)(ws + WS_QW2P + c*256 + o4);
            qwv.x += p.x; qwv.y += p.y; qwv.z += p.z; qwv.w += p.w;
        }
        float4 b1v = *(const float4*)(b1 + o4);
        #pragma unroll
        for (int lr = 0; lr < 8; ++lr) {
            float pp = gelu_tanh(z[lr][0]+b1v.x)*qwv.x + gelu_tanh(z[lr][1]+b1v.y)*qwv.y
                     + gelu_tanh(z[lr][2]+b1v.z)*qwv.z + gelu_tanh(z[lr][3]+b1v.w)*qwv.w;
            #pragma unroll
            for (int off = 32; off > 0; off >>= 1) pp += __shfl_xor(pp, off);
            if (lane == 0) pq_s[w*8 + lr] = pp;
        }
    }
    LGKMBAR();                         // pq_s visible

    float qkr[8];
    #pragma unroll
    for (int i2 = 0; i2 < 8; ++i2) qkr[i2] = qk_s[i2*32 + dld];

    // ---- main loop over n (fully unrolled: all vb indices static)
    #pragma unroll
    for (int n = 0; n < 16; ++n) {
        const float4 (&vc)[8] = vb[n & 1];
        // score partials: this thread's 32 d x its 4 l
        float sp0=0.f, sp1=0.f, sp2=0.f, sp3=0.f;
        #pragma unroll
        for (int i2 = 0; i2 < 8; ++i2) {
            sp0 += vc[i2].x * qkr[i2];
            sp1 += vc[i2].y * qkr[i2];
            sp2 += vc[i2].z * qkr[i2];
            sp3 += vc[i2].w * qkr[i2];
        }
        // reduce over the 8 dld-groups in this wave (lane bits 3,4,5)
        sp0 += __shfl_xor(sp0, 8); sp0 += __shfl_xor(sp0, 16); sp0 += __shfl_xor(sp0, 32);
        sp1 += __shfl_xor(sp1, 8); sp1 += __shfl_xor(sp1, 16); sp1 += __shfl_xor(sp1, 32);
        sp2 += __shfl_xor(sp2, 8); sp2 += __shfl_xor(sp2, 16); sp2 += __shfl_xor(sp2, 32);
        sp3 += __shfl_xor(sp3, 8); sp3 += __shfl_xor(sp3, 16); sp3 += __shfl_xor(sp3, 32);
        if (lane < 8) {
            float4 s4; s4.x=sp0; s4.y=sp1; s4.z=sp2; s4.w=sp3;
            *(float4*)(part + w*32 + li4) = s4;   // wave partial over its 64 d
        }
        LGKMBAR();
        if (t < 32) {                  // single-shot softmax for 32 scores
            float dot = part[t] + part[32+t] + part[64+t] + part[96+t];
            float score = (dot + pq_s[t]) * 0.0625f;
            float mc = score;
            #pragma unroll
            for (int off = 16; off > 0; off >>= 1) mc = fmaxf(mc, __shfl_xor(mc, off));
            float e = expf(score - mc);
            e_s[t] = e;
            float dc = e;
            #pragma unroll
            for (int off = 16; off > 0; off >>= 1) dc += __shfl_xor(dc, off);
            if (t == 0) {
                ws[WS_M + n*512 + lb] = mc;
                ws[WS_DEN + n*512 + lb] = dc;
            }
        }
        LGKMBAR();
        float4 e4 = *(const float4*)(e_s + li4);
        float na[8];
        #pragma unroll
        for (int i2 = 0; i2 < 8; ++i2)
            na[i2] = e4.x*vc[i2].x + e4.y*vc[i2].y + e4.z*vc[i2].z + e4.w*vc[i2].w;
        // reduce over the 8 lanes sharing a d (lane bits 0..2)
        #pragma unroll
        for (int i2 = 0; i2 < 8; ++i2) {
            na[i2] += __shfl_xor(na[i2], 1);
            na[i2] += __shfl_xor(na[i2], 2);
            na[i2] += __shfl_xor(na[i2], 4);
        }
        if ((t & 7) == 0) {
            #pragma unroll
            for (int i2 = 0; i2 < 8; ++i2)
                ws[WS_NUM + ((size_t)n*512 + lb)*256 + i2*32 + dld] = na[i2];
        }
        if (n + 2 < 16) {              // refill the buffer just consumed
            #pragma unroll
            for (int i2 = 0; i2 < 8; ++i2)
                vb[n & 1][i2] = *(const float4*)(xb
                    + ((size_t)((n+2)*DD + i2*32 + dld))*LL);
        }
    }

    // ---- ticketed tail: last 16 blocks each combine one n (replaces k3)
    __threadfence();                   // release partials (device scope, L2 wb)
    if (t == 0) ticket_s = atomicAdd((unsigned*)(ws + WS_CNT), 1u);
    __syncthreads();
    unsigned ticket = ticket_s;
    if (ticket < 496u) return;
    int nn = (int)ticket - 496;
    if (t == 0) {
        while (atomicAdd((unsigned*)(ws + WS_CNT), 0u) < 512u)
            __builtin_amdgcn_s_sleep(2);
    }
    __syncthreads();
    __threadfence();                   // acquire: see all blocks' partials
    // LDS overlay on featsT (done with it): red|e_sc|s_s|sp = 8 KB
    float* red  = featsT;              // 256
    float* e_sc = featsT + 256;        // 512
    float* s_s  = featsT + 768;        // 256
    float* spb  = featsT + 1024;       // 1024
    const float* Mp = ws + WS_M + nn*512;
    const float* Dp = ws + WS_DEN + nn*512;
    float m0 = Mp[t], m1 = Mp[t+256];
    red[t] = fmaxf(m0, m1);
    __syncthreads();
    for (int s = 128; s > 0; s >>= 1) {
        if (t < s) red[t] = fmaxf(red[t], red[t+s]);
        __syncthreads();
    }
    float m = red[0];
    __syncthreads();
    float e0 = expf(m0 - m), e1 = expf(m1 - m);
    e_sc[t] = e0; e_sc[t+256] = e1;
    red[t] = Dp[t]*e0 + Dp[t+256]*e1;
    __syncthreads();
    for (int s = 128; s > 0; s >>= 1) {
        if (t < s) red[t] += red[t+s];
        __syncthreads();
    }
    float den = red[0];
    __syncthreads();
    const float* NBp = ws + WS_NUM + (size_t)nn*512*256;
    float ax=0.f, ay=0.f, az=0.f, aw=0.f;
    #pragma unroll 4
    for (int i = 0; i < 128; ++i) {
        int lbq = w*128 + i;
        float sc = e_sc[lbq];
        float4 v4 = *(const float4*)(NBp + (size_t)lbq*256 + lane*4);
        ax += sc*v4.x; ay += sc*v4.y; az += sc*v4.z; aw += sc*v4.w;
    }
    { float4 a4; a4.x=ax; a4.y=ay; a4.z=az; a4.w=aw;
      *(float4*)(spb + w*256 + lane*4) = a4; }
    __syncthreads();
    s_s[t] = (spb[t] + spb[256+t] + spb[512+t] + spb[768+t]) / den;
    __syncthreads();
    float acc = v_b[t];
    #pragma unroll 8
    for (int d = 0; d < 256; ++d)
        acc += ws[WS_VWT + d*DO + t] * s_s[d];   // coalesced over t, s broadcast
    out[nn*DO + t] = acc;
}

extern "C" void kernel_launch(void* const* d_in, const int* in_sizes, int n_in,
                              void* d_out, int out_size, void* d_ws, size_t ws_size,
                              hipStream_t stream) {
    const float* x     = (const float*)d_in[0];
    const float* query = (const float*)d_in[1];
    const float* k_w   = (const float*)d_in[2];
    const float* v_w   = (const float*)d_in[4];
    const float* v_b   = (const float*)d_in[5];
    const float* Wr    = (const float*)d_in[6];
    const float* w1    = (const float*)d_in[7];
    const float* b1    = (const float*)d_in[8];
    const float* w2    = (const float*)d_in[9];
    float* ws  = (float*)d_ws;
    float* out = (float*)d_out;

    k0<<<528, 256, 0, stream>>>(query, k_w, w2, w1, v_w, ws);
    k2_fused<<<512, 256, 0, stream>>>(x, Wr, b1, v_b, out, ws);
}

// Round 6
// 434.035 us; speedup vs baseline: 1.2037x; 1.2037x over previous
//
#include <hip/hip_runtime.h>
#include <math.h>

#define NB 16
#define DD 256       // D (in channels)
#define LL 16384     // H*W
#define DO 256       // D_OUT

// workspace float offsets
#define WS_QKP   0                    // 8*256 qk partials
#define WS_QW2P  2048                 // 8*256 qw2 partials
#define WS_W1T   4096                 // 65536  w1t[f][o]
#define WS_VWT   (WS_W1T + 65536)     // 65536  v_wt[d][o]
#define WS_M     (WS_VWT + 65536)     // 16*512
#define WS_DEN   (WS_M + NB*512)      // 16*512
#define WS_NUM   (WS_DEN + NB*512)    // 16*512*256 = 2097152
// total ~2.25M floats (~9 MB) of d_ws

__device__ __forceinline__ float gelu_tanh(float u) {
    float u3 = u*u*u;
    return 0.5f*u*(1.0f + tanhf(0.7978845608028654f*(u + 0.044715f*u3)));
}

// LDS-only barrier: NO vmcnt drain (keeps global prefetch loads in flight).
// Producer-safe: own ds_writes retired (lgkmcnt 0) before s_barrier.
#define LGKMBAR() do {                                          \
    asm volatile("s_waitcnt lgkmcnt(0)" ::: "memory");          \
    __builtin_amdgcn_s_barrier();                               \
    asm volatile("" ::: "memory");                              \
} while (0)

// ---- K0: grid 528.
// blocks 0..7   : qk partial over o-chunk   (k_w^T q)
// blocks 8..15  : qw2 partial over o-chunk  (w2^T q)
// blocks 16..271: w1t[f][o] = w1[o][f]
// blocks 272..527: v_wt[d][o] = v_w[o][d]
// c1=k_b.q, c2=b2.q are constant over l,n -> softmax-invariant -> dropped.
__global__ __launch_bounds__(256) void k0(const float* __restrict__ query,
        const float* __restrict__ k_w, const float* __restrict__ w2,
        const float* __restrict__ w1, const float* __restrict__ v_w,
        float* __restrict__ ws) {
    int t = threadIdx.x, b = blockIdx.x;
    if (b < 16) {
        bool is_k = (b < 8);
        int c = b & 7;
        const float* M = is_k ? k_w : w2;
        float a = 0.f;
        #pragma unroll
        for (int oi = 0; oi < 32; ++oi) {
            int o = c*32 + oi;
            a += M[o*DD + t] * query[o];    // row coalesced, query[o] scalar
        }
        ws[(is_k ? WS_QKP : WS_QW2P) + c*256 + t] = a;
    } else if (b < 272) {
        int f = b - 16;
        ws[WS_W1T + f*DO + t] = w1[t*DO + f];
    } else {
        int d = b - 272;
        ws[WS_VWT + d*DO + t] = v_w[t*DD + d];
    }
}

// ---- K2 fused: grid 512 (lb), 256 threads. Block owns l = lb*32 .. +32,
// loops over all 16 n. Prologue computes pq for its 32 l (MLP, w1t from L2).
// Softmax is FULLY PARALLEL in-register: each thread computes the 4 scores
// for its own l's from part[] broadcasts, reduces max/den over its 8-lane
// group (which spans all 32 l), and keeps e in regs for the na phase.
// part[] is double-buffered by n -> ONE barrier per n-iteration, no WAR.
__global__ __launch_bounds__(256) void k2_fused(const float* __restrict__ x,
        const float* __restrict__ Wr, const float* __restrict__ b1,
        float* __restrict__ ws) {
    __shared__ __align__(16) float featsT[256*36];   // 36 KB: [f][32 l pad 36]
    __shared__ float qk_s[DD];
    __shared__ float pq_s[32];
    __shared__ __align__(16) float part[2][128];
    int t = threadIdx.x;
    int lb = blockIdx.x;
    int l0 = lb * 32;
    int w = t >> 6, lane = t & 63;
    int dld = t >> 3, li4 = (t & 7) * 4;   // thread owns d=i2*32+dld, l=l0+li4..+3
    const float* xb = x + l0 + li4;

    // issue x prefetch for n=0,1 immediately (flows under the prologue)
    float4 vb[2][8];
    #pragma unroll
    for (int i2 = 0; i2 < 8; ++i2)
        vb[0][i2] = *(const float4*)(xb + ((size_t)(0*DD + i2*32 + dld))*LL);
    #pragma unroll
    for (int i2 = 0; i2 < 8; ++i2)
        vb[1][i2] = *(const float4*)(xb + ((size_t)(1*DD + i2*32 + dld))*LL);

    // qk_s[t] = sum of 8 partials
    float aqk = 0.f;
    #pragma unroll
    for (int c = 0; c < 8; ++c) aqk += ws[WS_QKP + c*256 + t];
    qk_s[t] = aqk;

    // featsT[f][lr]: f = t, lr = 0..31 (cos for t<128, sin else)
    {
        int r = t & 127;
        float wr0 = Wr[r*2], wr1 = Wr[r*2+1];
        bool is_cos = (t < 128);
        #pragma unroll 8
        for (int lr = 0; lr < 32; ++lr) {
            int l = l0 + lr;
            int i = l >> 7, j = l & 127;
            float y = -1.0f + (2.0f/127.0f)*(float)i;
            float xg = -1.0f + (2.0f/127.0f)*(float)j;
            float p = y*wr0 + xg*wr1;
            featsT[t*36 + lr] = (is_cos ? cosf(p) : sinf(p)) * 0.0625f;
        }
    }
    LGKMBAR();                         // featsT + qk_s visible

    // ---- MLP prologue: wave w owns l = l0 + w*8 .. +8; lane owns o4 = lane*4.
    // wv streamed from ws[W1T] (L2/L3-resident, shared across waves).
    float z[8][4];
    #pragma unroll
    for (int a = 0; a < 8; ++a) { z[a][0]=0.f; z[a][1]=0.f; z[a][2]=0.f; z[a][3]=0.f; }
    int o4 = lane * 4;
    const float* w1p = ws + WS_W1T + o4;
    const float* frp = featsT + w*8;
    #pragma unroll 4
    for (int f = 0; f < 256; ++f) {
        float4 wv = *(const float4*)(w1p + f*256);       // global b128, L1/L2
        float4 fa = *(const float4*)(frp + f*36);        // LDS broadcast b128
        float4 fbq = *(const float4*)(frp + f*36 + 4);   // LDS broadcast b128
        float fv[8] = {fa.x,fa.y,fa.z,fa.w,fbq.x,fbq.y,fbq.z,fbq.w};
        #pragma unroll
        for (int lr = 0; lr < 8; ++lr) {
            z[lr][0] += fv[lr]*wv.x; z[lr][1] += fv[lr]*wv.y;
            z[lr][2] += fv[lr]*wv.z; z[lr][3] += fv[lr]*wv.w;
        }
    }
    {
        float4 qwv; qwv.x=0.f; qwv.y=0.f; qwv.z=0.f; qwv.w=0.f;
        #pragma unroll
        for (int c = 0; c < 8; ++c) {
            float4 p = *(const float4*)(ws + WS_QW2P + c*256 + o4);
            qwv.x += p.x; qwv.y += p.y; qwv.z += p.z; qwv.w += p.w;
        }
        float4 b1v = *(const float4*)(b1 + o4);
        #pragma unroll
        for (int lr = 0; lr < 8; ++lr) {
            float pp = gelu_tanh(z[lr][0]+b1v.x)*qwv.x + gelu_tanh(z[lr][1]+b1v.y)*qwv.y
                     + gelu_tanh(z[lr][2]+b1v.z)*qwv.z + gelu_tanh(z[lr][3]+b1v.w)*qwv.w;
            #pragma unroll
            for (int off = 32; off > 0; off >>= 1) pp += __shfl_xor(pp, off);
            if (lane == 0) pq_s[w*8 + lr] = pp;
        }
    }
    LGKMBAR();                         // pq_s visible

    float qkr[8];
    #pragma unroll
    for (int i2 = 0; i2 < 8; ++i2) qkr[i2] = qk_s[i2*32 + dld];
    // hoist this thread's 4 pq values (constant over n)
    float pq0 = pq_s[li4+0], pq1 = pq_s[li4+1], pq2 = pq_s[li4+2], pq3 = pq_s[li4+3];

    // ---- main loop over n (fully unrolled: all vb indices static)
    #pragma unroll
    for (int n = 0; n < 16; ++n) {
        const float4 (&vc)[8] = vb[n & 1];
        float* pbuf = part[n & 1];
        // score partials: this thread's 32 d x its 4 l
        float sp0=0.f, sp1=0.f, sp2=0.f, sp3=0.f;
        #pragma unroll
        for (int i2 = 0; i2 < 8; ++i2) {
            sp0 += vc[i2].x * qkr[i2];
            sp1 += vc[i2].y * qkr[i2];
            sp2 += vc[i2].z * qkr[i2];
            sp3 += vc[i2].w * qkr[i2];
        }
        // reduce over the 8 dld-groups in this wave (lane bits 3,4,5)
        sp0 += __shfl_xor(sp0, 8); sp0 += __shfl_xor(sp0, 16); sp0 += __shfl_xor(sp0, 32);
        sp1 += __shfl_xor(sp1, 8); sp1 += __shfl_xor(sp1, 16); sp1 += __shfl_xor(sp1, 32);
        sp2 += __shfl_xor(sp2, 8); sp2 += __shfl_xor(sp2, 16); sp2 += __shfl_xor(sp2, 32);
        sp3 += __shfl_xor(sp3, 8); sp3 += __shfl_xor(sp3, 16); sp3 += __shfl_xor(sp3, 32);
        if (lane < 8) {
            float4 s4; s4.x=sp0; s4.y=sp1; s4.z=sp2; s4.w=sp3;
            *(float4*)(pbuf + w*32 + li4) = s4;   // wave partial over its 64 d
        }
        LGKMBAR();                     // the ONLY barrier this iteration
        // parallel softmax: each thread builds its own 4 scores
        float d0 = pbuf[li4+0] + pbuf[32+li4+0] + pbuf[64+li4+0] + pbuf[96+li4+0];
        float d1 = pbuf[li4+1] + pbuf[32+li4+1] + pbuf[64+li4+1] + pbuf[96+li4+1];
        float d2 = pbuf[li4+2] + pbuf[32+li4+2] + pbuf[64+li4+2] + pbuf[96+li4+2];
        float d3 = pbuf[li4+3] + pbuf[32+li4+3] + pbuf[64+li4+3] + pbuf[96+li4+3];
        float s0 = (d0 + pq0) * 0.0625f;
        float s1 = (d1 + pq1) * 0.0625f;
        float s2 = (d2 + pq2) * 0.0625f;
        float s3 = (d3 + pq3) * 0.0625f;
        float mx = fmaxf(fmaxf(s0, s1), fmaxf(s2, s3));
        mx = fmaxf(mx, __shfl_xor(mx, 1));
        mx = fmaxf(mx, __shfl_xor(mx, 2));
        mx = fmaxf(mx, __shfl_xor(mx, 4));   // max over all 32 l
        float e0 = expf(s0 - mx), e1 = expf(s1 - mx);
        float e2 = expf(s2 - mx), e3 = expf(s3 - mx);
        float den = e0 + e1 + e2 + e3;
        den += __shfl_xor(den, 1);
        den += __shfl_xor(den, 2);
        den += __shfl_xor(den, 4);           // sum over all 32 l
        if (t == 0) {
            ws[WS_M + n*512 + lb] = mx;
            ws[WS_DEN + n*512 + lb] = den;
        }
        // num partials with in-register e weights
        float na[8];
        #pragma unroll
        for (int i2 = 0; i2 < 8; ++i2)
            na[i2] = e0*vc[i2].x + e1*vc[i2].y + e2*vc[i2].z + e3*vc[i2].w;
        // reduce over the 8 lanes sharing a d (lane bits 0..2)
        #pragma unroll
        for (int i2 = 0; i2 < 8; ++i2) {
            na[i2] += __shfl_xor(na[i2], 1);
            na[i2] += __shfl_xor(na[i2], 2);
            na[i2] += __shfl_xor(na[i2], 4);
        }
        if ((t & 7) == 0) {
            #pragma unroll
            for (int i2 = 0; i2 < 8; ++i2)
                ws[WS_NUM + ((size_t)n*512 + lb)*256 + i2*32 + dld] = na[i2];
        }
        if (n + 2 < 16) {              // refill the buffer just consumed
            #pragma unroll
            for (int i2 = 0; i2 < 8; ++i2)
                vb[n & 1][i2] = *(const float4*)(xb
                    + ((size_t)((n+2)*DD + i2*32 + dld))*LL);
        }
    }
}

// ---- K3: combine 512 partials per n, then out[n,o] = v_wt.s + v_b.
// grid 64: (n = b>>2, oq = b&3). Waves split lb; float4 over d.
__global__ __launch_bounds__(256) void k3_final(const float* __restrict__ ws,
        const float* __restrict__ v_b, float* __restrict__ out) {
    __shared__ float red[256];
    __shared__ float e_sc[512];
    __shared__ float s_s[DD];
    __shared__ __align__(16) float sp[4*256];
    int t = threadIdx.x, n = blockIdx.x >> 2, oq = blockIdx.x & 3;
    const float* Mp = ws + WS_M + n*512;
    const float* Dp = ws + WS_DEN + n*512;
    float m0 = Mp[t], m1 = Mp[t+256];
    red[t] = fmaxf(m0, m1);
    __syncthreads();
    for (int s = 128; s > 0; s >>= 1) {
        if (t < s) red[t] = fmaxf(red[t], red[t+s]);
        __syncthreads();
    }
    float m = red[0];
    __syncthreads();                   // everyone got m before red reuse
    float e0 = expf(m0 - m), e1 = expf(m1 - m);
    e_sc[t] = e0; e_sc[t+256] = e1;
    red[t] = Dp[t]*e0 + Dp[t+256]*e1;
    __syncthreads();
    for (int s = 128; s > 0; s >>= 1) {
        if (t < s) red[t] += red[t+s];
        __syncthreads();
    }
    float den = red[0];
    __syncthreads();
    // s partials: wave w sums lb = w*128..+128; lane owns d = lane*4..+3
    int w = t >> 6, lane = t & 63;
    const float* NBp = ws + WS_NUM + (size_t)n*512*256;
    float ax=0.f, ay=0.f, az=0.f, aw=0.f;
    #pragma unroll 4
    for (int i = 0; i < 128; ++i) {
        int lbq = w*128 + i;
        float sc = e_sc[lbq];
        float4 v4 = *(const float4*)(NBp + (size_t)lbq*256 + lane*4);
        ax += sc*v4.x; ay += sc*v4.y; az += sc*v4.z; aw += sc*v4.w;
    }
    { float4 a4; a4.x=ax; a4.y=ay; a4.z=az; a4.w=aw;
      *(float4*)(sp + w*256 + lane*4) = a4; }
    __syncthreads();
    s_s[t] = (sp[t] + sp[256+t] + sp[512+t] + sp[768+t]) / den;
    __syncthreads();
    // out: wave w sums d = w*64..+64 for o = oq*64 + lane
    int o = oq*64 + lane;
    float acc = 0.f;
    #pragma unroll 8
    for (int i = 0; i < 64; ++i) {
        int d = w*64 + i;
        acc += ws[WS_VWT + d*DO + o] * s_s[d];   // coalesced, s broadcast
    }
    red[t] = acc;
    __syncthreads();
    if (t < 64)
        out[n*DO + oq*64 + t] = v_b[oq*64 + t]
            + red[t] + red[64+t] + red[128+t] + red[192+t];
}

extern "C" void kernel_launch(void* const* d_in, const int* in_sizes, int n_in,
                              void* d_out, int out_size, void* d_ws, size_t ws_size,
                              hipStream_t stream) {
    const float* x     = (const float*)d_in[0];
    const float* query = (const float*)d_in[1];
    const float* k_w   = (const float*)d_in[2];
    const float* v_w   = (const float*)d_in[4];
    const float* v_b   = (const float*)d_in[5];
    const float* Wr    = (const float*)d_in[6];
    const float* w1    = (const float*)d_in[7];
    const float* b1    = (const float*)d_in[8];
    const float* w2    = (const float*)d_in[9];
    float* ws  = (float*)d_ws;
    float* out = (float*)d_out;

    k0<<<528, 256, 0, stream>>>(query, k_w, w2, w1, v_w, ws);
    k2_fused<<<512, 256, 0, stream>>>(x, Wr, b1, ws);
    k3_final<<<64, 256, 0, stream>>>(ws, v_b, out);
}